// Round 3
// baseline (100.970 us; speedup 1.0000x reference)
//
#include <hip/hip_runtime.h>

#define NB 2048
#define BS 256
#define NWAVES (BS / 64)

typedef float vfloat4 __attribute__((ext_vector_type(4)));

// exp(-0.5*((d-2)/4)^2) = exp2(K2 * (d-2)^2), K2 = -0.5/16 * log2(e)
#define K2EXP (-0.045084219f)

__device__ __forceinline__ void process_point(
    float px, float py, float cx, float cy,
    float v0x, float v0y, float v1x, float v1y, float v2x, float v2y,
    float e0x, float e0y, float e1x, float e1y, float e2x, float e2y,
    float& sum_g, float& cnt) {
  const float dx = cx - px, dy = cy - py;
  const float d = __builtin_amdgcn_sqrtf(dx * dx + dy * dy);
  const float dm = d - 2.0f;
  sum_g += __builtin_amdgcn_exp2f(K2EXP * dm * dm);
  // triangle is CCW (orientation preserved by rotation): inside <=> all cross > 0
  const float c0 = e0x * (py - v0y) - e0y * (px - v0x);
  const float c1 = e1x * (py - v1y) - e1y * (px - v1x);
  const float c2 = e2x * (py - v2y) - e2y * (px - v2x);
  cnt += (c0 > 0.f && c1 > 0.f && c2 > 0.f) ? 1.f : 0.f;
}

__global__ __launch_bounds__(BS) void reduce_kernel(
    const float* __restrict__ pts, const float* __restrict__ cam,
    float* __restrict__ partials, int n_points) {
  const float cx = cam[0], cy = cam[1], yaw = cam[2];
  const float c = cosf(yaw), s = sinf(yaw);
  const float v0x = cx,                      v0y = cy;
  const float v1x = 2.f * c - 7.f * s + cx,  v1y = 2.f * s + 7.f * c + cy;
  const float v2x = -2.f * c - 7.f * s + cx, v2y = -2.f * s + 7.f * c + cy;
  const float e0x = v1x - v0x, e0y = v1y - v0y;
  const float e1x = v2x - v1x, e1y = v2y - v1y;
  const float e2x = v0x - v2x, e2y = v0y - v2y;

  float sum_g = 0.f, cnt = 0.f;

  const int tid = blockIdx.x * BS + threadIdx.x;
  const int stride = NB * BS;
  const int n4 = n_points >> 1;  // one vfloat4 = 2 points
  const vfloat4* __restrict__ p4 = (const vfloat4*)pts;

  int i = tid;
  // 2x unrolled main loop: two independent 16B loads in flight
  for (; i + stride < n4; i += 2 * stride) {
    const vfloat4 a = __builtin_nontemporal_load(&p4[i]);
    const vfloat4 b = __builtin_nontemporal_load(&p4[i + stride]);
    process_point(a.x, a.y, cx, cy, v0x, v0y, v1x, v1y, v2x, v2y,
                  e0x, e0y, e1x, e1y, e2x, e2y, sum_g, cnt);
    process_point(a.z, a.w, cx, cy, v0x, v0y, v1x, v1y, v2x, v2y,
                  e0x, e0y, e1x, e1y, e2x, e2y, sum_g, cnt);
    process_point(b.x, b.y, cx, cy, v0x, v0y, v1x, v1y, v2x, v2y,
                  e0x, e0y, e1x, e1y, e2x, e2y, sum_g, cnt);
    process_point(b.z, b.w, cx, cy, v0x, v0y, v1x, v1y, v2x, v2y,
                  e0x, e0y, e1x, e1y, e2x, e2y, sum_g, cnt);
  }
  for (; i < n4; i += stride) {
    const vfloat4 a = __builtin_nontemporal_load(&p4[i]);
    process_point(a.x, a.y, cx, cy, v0x, v0y, v1x, v1y, v2x, v2y,
                  e0x, e0y, e1x, e1y, e2x, e2y, sum_g, cnt);
    process_point(a.z, a.w, cx, cy, v0x, v0y, v1x, v1y, v2x, v2y,
                  e0x, e0y, e1x, e1y, e2x, e2y, sum_g, cnt);
  }
  // odd-N tail (not hit for N=8M)
  if (tid == 0 && (n_points & 1)) {
    process_point(pts[2 * (n_points - 1)], pts[2 * (n_points - 1) + 1],
                  cx, cy, v0x, v0y, v1x, v1y, v2x, v2y,
                  e0x, e0y, e1x, e1y, e2x, e2y, sum_g, cnt);
  }

  // wave (64-lane) shuffle reduction
  for (int off = 32; off > 0; off >>= 1) {
    sum_g += __shfl_down(sum_g, off, 64);
    cnt += __shfl_down(cnt, off, 64);
  }
  __shared__ float ls[NWAVES], lc[NWAVES];
  const int lane = threadIdx.x & 63, wid = threadIdx.x >> 6;
  if (lane == 0) { ls[wid] = sum_g; lc[wid] = cnt; }
  __syncthreads();
  if (threadIdx.x == 0) {
    float S = 0.f, C = 0.f;
    for (int w = 0; w < NWAVES; ++w) { S += ls[w]; C += lc[w]; }
    partials[blockIdx.x] = S;
    partials[NB + blockIdx.x] = C;
  }
}

__global__ __launch_bounds__(BS) void finalize_kernel(
    const float* __restrict__ partials, float* __restrict__ out) {
  float S = 0.f, C = 0.f;
  for (int i = threadIdx.x; i < NB; i += BS) {
    S += partials[i];
    C += partials[NB + i];
  }
  for (int off = 32; off > 0; off >>= 1) {
    S += __shfl_down(S, off, 64);
    C += __shfl_down(C, off, 64);
  }
  __shared__ float ls[NWAVES], lc[NWAVES];
  const int lane = threadIdx.x & 63, wid = threadIdx.x >> 6;
  if (lane == 0) { ls[wid] = S; lc[wid] = C; }
  __syncthreads();
  if (threadIdx.x == 0) {
    float St = 0.f, Ct = 0.f;
    for (int w = 0; w < NWAVES; ++w) { St += ls[w]; Ct += lc[w]; }
    const float K = 0.09973557010f;  // 1/(4*sqrt(2*pi))
    const float eps = 1e-6f;
    out[0] = 1.0f / (St * K + eps) + 1.0f / (Ct + eps);
  }
}

extern "C" void kernel_launch(void* const* d_in, const int* in_sizes, int n_in,
                              void* d_out, int out_size, void* d_ws, size_t ws_size,
                              hipStream_t stream) {
  const float* pts = (const float*)d_in[0];
  const float* cam = (const float*)d_in[1];
  float* out = (float*)d_out;
  float* partials = (float*)d_ws;  // 2*NB floats = 16 KB
  const int n_points = in_sizes[0] / 2;

  reduce_kernel<<<NB, BS, 0, stream>>>(pts, cam, partials, n_points);
  finalize_kernel<<<1, BS, 0, stream>>>(partials, out);
}